// Round 2
// baseline (65.620 us; speedup 1.0000x reference)
//
#include <hip/hip_runtime.h>
#include <math.h>

#define TWO_PI_F 6.2831853071795864769f
#define EPS_F 1e-6f
#define PI_F 3.14159265358979323846f

__device__ __forceinline__ void kent_frame(float eta, float alpha, float psi,
                                           float& g1x, float& g1y, float& g1z,
                                           float& g2x, float& g2y, float& g2z,
                                           float& g3x, float& g3y, float& g3z) {
    float ca = cosf(alpha), sa = sinf(alpha);
    float ce = cosf(eta),   se = sinf(eta);
    float cp = cosf(psi),   sp = sinf(psi);
    g1x = ca;        g1y = sa * ce;                  g1z = sa * se;
    g2x = -cp * sa;  g2y = cp * ca * ce - sp * se;   g2z = cp * ca * se + sp * ce;
    g3x = sp * sa;   g3y = -sp * ca * ce - cp * se;  g3z = -sp * ca * se + cp * ce;
}

// Fully fused: one dispatch, no workspace.
// Block = 256 threads. Tile = 8 n-rows x 1024 m-cols.
//   lanes 0..7: per-n features {Ex(3), Sdiag(3), 2*Soff(3), A} -> LDS
//   all threads: per-m features {kb*gb1(3), bb*Ddiag(3), bb*Doff(3), c_b}
//                for 4 consecutive m in registers
//   epilogue: out[n,m] = A[n] + c_b[m] - sum_k f[n,k]*g[m,k]
__global__ __launch_bounds__(256) void kent_kld_fused(
    const float* __restrict__ pred, const float* __restrict__ targ,
    float* __restrict__ out, int N, int M)
{
    __shared__ float fsh[8][10];

    int t  = threadIdx.x;
    int n0 = blockIdx.y * 8;
    int m0 = blockIdx.x * 1024 + t * 4;

    // ---- Phase A: per-n features (lanes 0..7 of wave 0) ----
    if (t < 8 && (n0 + t) < N) {
        const float* r = pred + (size_t)(n0 + t) * 5;
        float eta = r[0], alpha = r[1], psi = r[2], kap = r[3], bet = r[4];
        float g1x,g1y,g1z,g2x,g2y,g2z,g3x,g3y,g3z;
        kent_frame(eta, alpha, psi, g1x,g1y,g1z, g2x,g2y,g2z, g3x,g3y,g3z);

        float km = kap - 2.f*bet, kp = kap + 2.f*bet;
        float lkm = logf(km), lkp = logf(kp);
        float c   = logf(TWO_PI_F) + kap - 0.5f*logf(km*kp + EPS_F);
        float b2 = bet*bet;
        float ck  = logf(TWO_PI_F*(kap*kap - kap - 4.f*b2)) + kap
                  - (1.5f*lkm + 1.5f*lkp + EPS_F);
        float k2 = kap*kap;
        float poly = k2*k2 - 2.f*kap*k2 + (2.f - 8.f*b2)*k2 + 8.f*b2*kap
                   + 16.f*b2*b2 + 4.f*b2;
        float ckk = logf(TWO_PI_F*poly) + kap - (2.5f*lkm + 2.5f*lkp + EPS_F);
        float cbt = logf(8.f*PI_F*kap) + logf(bet) - (1.5f*lkm + 1.5f*lkp + EPS_F);

        float l1  = expf(ck  - c);
        float ekk = expf(ckk - c);
        float eb  = expf(cbt - c);
        float l2 = 0.5f*(1.f - ekk + eb);
        float l3 = 0.5f*(1.f - ekk - eb);

        float Ex = l1*g1x, Ey = l1*g1y, Ez = l1*g1z;
        float S00 = l1*g1x*g1x + l2*g2x*g2x + l3*g3x*g3x;
        float S11 = l1*g1y*g1y + l2*g2y*g2y + l3*g3y*g3y;
        float S22 = l1*g1z*g1z + l2*g2z*g2z + l3*g3z*g3z;
        float S01 = l1*g1x*g1y + l2*g2x*g2y + l3*g3x*g3y;
        float S02 = l1*g1x*g1z + l2*g2x*g2z + l3*g3x*g3z;
        float S12 = l1*g1y*g1z + l2*g2y*g2z + l3*g3y*g3z;

        float qa2 = S00*g2x*g2x + S11*g2y*g2y + S22*g2z*g2z
                  + 2.f*(S01*g2x*g2y + S02*g2x*g2z + S12*g2y*g2z);
        float qa3 = S00*g3x*g3x + S11*g3y*g3y + S22*g3z*g3z
                  + 2.f*(S01*g3x*g3y + S02*g3x*g3z + S12*g3y*g3z);
        float dg1Ex = g1x*Ex + g1y*Ey + g1z*Ez;
        float A = -c + kap*dg1Ex + bet*(qa2 - qa3);

        fsh[t][0]=Ex;      fsh[t][1]=Ey;      fsh[t][2]=Ez;
        fsh[t][3]=S00;     fsh[t][4]=S11;     fsh[t][5]=S22;
        fsh[t][6]=2.f*S01; fsh[t][7]=2.f*S02; fsh[t][8]=2.f*S12;
        fsh[t][9]=A;
    }

    // ---- Phase B: per-m features for 4 columns (registers) ----
    float G[10][4];
#pragma unroll
    for (int j = 0; j < 4; ++j) {
        int m = m0 + j;
        if (m < M) {
            const float* r = targ + (size_t)m * 5;
            float eta = r[0], alpha = r[1], psi = r[2], kap = r[3], bet = r[4];
            float g1x,g1y,g1z,g2x,g2y,g2z,g3x,g3y,g3z;
            kent_frame(eta, alpha, psi, g1x,g1y,g1z, g2x,g2y,g2z, g3x,g3y,g3z);

            float km = kap - 2.f*bet, kp = kap + 2.f*bet;
            float cB = logf(TWO_PI_F) + kap - 0.5f*logf(km*kp + EPS_F);

            G[0][j] = kap*g1x;
            G[1][j] = kap*g1y;
            G[2][j] = kap*g1z;
            G[3][j] = bet*(g2x*g2x - g3x*g3x);
            G[4][j] = bet*(g2y*g2y - g3y*g3y);
            G[5][j] = bet*(g2z*g2z - g3z*g3z);
            G[6][j] = bet*(g2x*g2y - g3x*g3y);
            G[7][j] = bet*(g2x*g2z - g3x*g3z);
            G[8][j] = bet*(g2y*g2z - g3y*g3z);
            G[9][j] = cB;
        } else {
#pragma unroll
            for (int k = 0; k < 10; ++k) G[k][j] = 0.f;
        }
    }

    __syncthreads();

    if (m0 >= M) return;

    // ---- Phase C: rank-9 bilinear epilogue + coalesced float4 stores ----
#pragma unroll
    for (int rr = 0; rr < 8; ++rr) {
        int n = n0 + rr;
        if (n >= N) break;
        float A = fsh[rr][9];
        float4 o;
        o.x = A + G[9][0]; o.y = A + G[9][1];
        o.z = A + G[9][2]; o.w = A + G[9][3];
#pragma unroll
        for (int k = 0; k < 9; ++k) {
            float fk = fsh[rr][k];
            o.x = fmaf(-fk, G[k][0], o.x);
            o.y = fmaf(-fk, G[k][1], o.y);
            o.z = fmaf(-fk, G[k][2], o.z);
            o.w = fmaf(-fk, G[k][3], o.w);
        }
        if (m0 + 3 < M) {
            *(float4*)(&out[(size_t)n * M + m0]) = o;
        } else {
            float ov[4] = {o.x, o.y, o.z, o.w};
            for (int j = 0; j < 4 && m0 + j < M; ++j)
                out[(size_t)n * M + m0 + j] = ov[j];
        }
    }
}

extern "C" void kernel_launch(void* const* d_in, const int* in_sizes, int n_in,
                              void* d_out, int out_size, void* d_ws, size_t ws_size,
                              hipStream_t stream) {
    const float* pred = (const float*)d_in[0];
    const float* targ = (const float*)d_in[1];
    int N = in_sizes[0] / 5;
    int M = in_sizes[1] / 5;
    float* out = (float*)d_out;

    dim3 grid((M + 1023) / 1024, (N + 7) / 8);
    kent_kld_fused<<<grid, 256, 0, stream>>>(pred, targ, out, N, M);
}